// Round 1
// 100.341 us; speedup vs baseline: 1.0745x; 1.0745x over previous
//
#include <hip/hip_runtime.h>

#define F_ELEMS 2097152            // B*T*H*W = 4*8*256*256 (elements per field)
#define IMG 65536                  // H*W

typedef _Float16 half8  __attribute__((ext_vector_type(8)));
typedef _Float16 half2v __attribute__((ext_vector_type(2)));
typedef _Float16 half4v __attribute__((ext_vector_type(4)));
typedef float    floatx4 __attribute__((ext_vector_type(4)));

__device__ __forceinline__ float sigm(float x){ return 1.0f/(1.0f + __expf(-x)); }
__device__ __forceinline__ float tanh_fast(float x){
    float t = __expf(2.0f*x);
    return 1.0f - 2.0f/(t + 1.0f);
}

// ---------------------------------------------------------------------------
// K1: conv 3x3 (8ch -> 64ch) via MFMA f16 implicit GEMM, fused pointwise.
// Block: strip of 2 rows x 256 cols for one b; computes all 64 oc.
// K decomposition: MFMA 16x16x32: K=32 = 4 taps x 8 input channels.
// Fields stored f16: 0 kappa^2, 1 m1, 2 m2, 3 Hxx, 4 Hs, 5 Hyy, 6 tau.
// logdet reduction moved to K2 (field 6 carries tau); block (0,0) zeroes out.
// ---------------------------------------------------------------------------
__global__ __launch_bounds__(256) void conv_mfma(
    const float* __restrict__ x, const float* __restrict__ w,
    _Float16* __restrict__ fld, float* __restrict__ out)
{
    __shared__ _Float16 xt[4*258*8];     // 4 rows, 258 cols (halo), 8 ch
    __shared__ _Float16 Wl[12*64*8];     // [tap][oc][c]

    const int tid = threadIdx.x;
    const int i0  = blockIdx.x << 1;     // strip of 2 rows
    const int b   = blockIdx.y;

    // K2 runs after K1 in stream order, so this zero is safe (no atomics here).
    if (tid == 0 && blockIdx.x == 0 && blockIdx.y == 0) out[0] = 0.0f;

    // ---- stage x (f32 -> f16, channel pairs for 4B LDS writes) ----
    for (int e = tid; e < 258*4*4; e += 256){
        int cc = e % 258;
        int rr = (e/258) & 3;
        int cp = e / (258*4);            // channel pair 0..3
        int gi = i0 - 1 + rr, gj = cc - 1;
        float v0 = 0.0f, v1 = 0.0f;
        if (gi >= 0 && gi < 256 && gj >= 0 && gj < 256){
            int base = ((b*8 + 2*cp) << 16) + (gi << 8) + gj;
            v0 = x[base];
            v1 = x[base + IMG];
        }
        half2v h; h[0] = (_Float16)v0; h[1] = (_Float16)v1;
        *(half2v*)&xt[(rr*258 + cc)*8 + 2*cp] = h;
    }
    // ---- stage weights [tap][oc][c], zero-pad taps 9..11 ----
    for (int e = tid; e < 12*64*8; e += 256){
        int c  = e & 7;
        int oc = (e >> 3) & 63;
        int t  = e >> 9;
        float v = (t < 9) ? w[(oc*8 + c)*9 + t] : 0.0f;
        Wl[e] = (_Float16)v;             // e == (t*64+oc)*8 + c
    }
    __syncthreads();

    const int lane = tid & 63;
    const int quad = lane >> 4;
    const int l16  = lane & 15;
    const int wv   = tid >> 6;

    // A-frags: A[m=oc_local][k=quad*8+j] -> Wl[tap=s*4+quad][ot*16+l16][0..7]
    half8 afr[4][3];
    int boff[3];
    #pragma unroll
    for (int s = 0; s < 3; ++s){
        int t  = s*4 + quad;
        afr[0][s] = *(const half8*)&Wl[(t*64 +  0 + l16)*8];
        afr[1][s] = *(const half8*)&Wl[(t*64 + 16 + l16)*8];
        afr[2][s] = *(const half8*)&Wl[(t*64 + 32 + l16)*8];
        afr[3][s] = *(const half8*)&Wl[(t*64 + 48 + l16)*8];
        int tc = (t < 9) ? t : 8;        // taps >=9 have zero weights
        int dh = tc / 3, dw = tc - dh*3;
        boff[s] = (dh*258 + dw)*8;
    }

    // 32 groups of 16 px (2 rows x 16 col-groups); 8 iters per wave
    #pragma unroll 2
    for (int it = 0; it < 8; ++it){
        const int g   = it*4 + wv;
        const int r   = g >> 4;
        const int jb  = ((g & 15) << 4) + l16;   // image col of this lane's px
        const int xoff = (r*258 + jb)*8;

        floatx4 acc0 = {0,0,0,0}, acc1 = {0,0,0,0}, acc2 = {0,0,0,0}, acc3 = {0,0,0,0};
        #pragma unroll
        for (int s = 0; s < 3; ++s){
            half8 bf = *(const half8*)&xt[xoff + boff[s]];
            acc0 = __builtin_amdgcn_mfma_f32_16x16x32_f16(afr[0][s], bf, acc0, 0, 0, 0);
            acc1 = __builtin_amdgcn_mfma_f32_16x16x32_f16(afr[1][s], bf, acc1, 0, 0, 0);
            acc2 = __builtin_amdgcn_mfma_f32_16x16x32_f16(afr[2][s], bf, acc2, 0, 0, 0);
            acc3 = __builtin_amdgcn_mfma_f32_16x16x32_f16(afr[3][s], bf, acc3, 0, 0, 0);
        }

        // epilogue: lane holds oc = ot*16 + quad*4 + reg, px col = jb, row i0+r
        const int pix0 = (b << 19) + ((i0 + r) << 8) + jb;
#define STO(f, tt, v) fld[(f)*F_ELEMS + ((tt) << 16) + pix0] = (_Float16)(v)
        // ot=0: g0 kappa (quads 0,1) / g1 m1 (quads 2,3)
        #pragma unroll
        for (int rg = 0; rg < 4; ++rg){
            int oc = quad*4 + rg, tt = oc & 7;
            float v = acc0[rg];
            if (oc < 8){ float s = 0.99f*sigm(v) + 0.01f; STO(0, tt, s*s); }
            else       { STO(1, tt, v); }
        }
        // ot=1: g2 m2 / g3 Hxx
        #pragma unroll
        for (int rg = 0; rg < 4; ++rg){
            int oc = 16 + quad*4 + rg, tt = oc & 7;
            float v = acc1[rg];
            if (oc < 24){ STO(2, tt, v); }
            else        { STO(3, tt, 0.99f*sigm(v) + 0.01f); }
        }
        // ot=2: g4 Hxy / g5 Hyx -> Hs = 0.1(tanh+tanh), stored by quads 0,1
        #pragma unroll
        for (int rg = 0; rg < 4; ++rg){
            float th    = 0.1f*tanh_fast(acc2[rg]);
            float other = __shfl_xor(th, 32, 64);
            if (quad < 2){
                int tt = quad*4 + rg;            // oc = 32+quad*4+rg, tt = oc&7
                STO(4, tt, th + other);
            }
        }
        // ot=3: g6 Hyy / g7 tau (stored raw; K2 derives D and log tau)
        #pragma unroll
        for (int rg = 0; rg < 4; ++rg){
            int oc = 48 + quad*4 + rg, tt = oc & 7;
            float v = acc3[rg];
            if (oc < 56){ STO(5, tt, 0.99f*sigm(v) + 0.01f); }
            else {
                float tau = 9.9f*sigm(v) + 0.1f;
                STO(6, tt, tau);
            }
        }
#undef STO
    }
}

// ---------------------------------------------------------------------------
// A(u) with f16 coefficient fields.
// ---------------------------------------------------------------------------
__device__ __forceinline__ void ldf4(const _Float16* __restrict__ p, float o[4]){
    half4v h = *(const half4v*)p;
    o[0] = (float)h[0]; o[1] = (float)h[1]; o[2] = (float)h[2]; o[3] = (float)h[3];
}

__device__ __forceinline__ void row6(const float* __restrict__ u, int rb, int j0, float v[6]){
    const float4 c4 = *(const float4*)&u[rb + j0];
    v[1] = c4.x; v[2] = c4.y; v[3] = c4.z; v[4] = c4.w;
    v[0] = (j0 > 0)   ? u[rb + j0 - 1] : 0.0f;
    v[5] = (j0 < 252) ? u[rb + j0 + 4] : 0.0f;
}

__device__ __forceinline__ void stencil4(const float k2[4], const float m1[4],
    const float m2[4], const float hx[4], const float hs[4], const float hy[4],
    const float vc[6], const float vn[6], const float vs[6], float rp[4])
{
    #pragma unroll
    for (int p = 0; p < 4; ++p){
        float hxx = hx[p], hyy = hy[p];
        rp[p] = (k2[p] + 2.0f*(hxx + hyy))*vc[p+1]
              + (0.5f*m1[p] - hxx)*vc[p+2]
              - (0.5f*m1[p] + hxx)*vc[p]
              + (0.5f*m2[p] - hyy)*vn[p+1]
              - (0.5f*m2[p] + hyy)*vs[p+1]
              - 0.25f*hs[p]*(vn[p+2] - vs[p+2] - vn[p] + vs[p]);
    }
}

// ---------------------------------------------------------------------------
// K2: fused z = A(A(x)); r = x + z - x_prev;
// out += 0.5*sum(D r^2) + sum(log tau)   (== 0.5*(xQx - logdetD))
// Block: 16-row strip x 256 cols of one (b,t) image. y kept in LDS (18 rows
// incl. halo, recomputed per strip).
// ---------------------------------------------------------------------------
#define YSW 268
__global__ __launch_bounds__(256) void fused_A(
    const float* __restrict__ x, const _Float16* __restrict__ fld,
    float* __restrict__ out)
{
    __shared__ float ys[18*YSW];
    __shared__ float redA[4], redB[4];

    const int tid = threadIdx.x;
    const int cg  = tid & 63;            // col group (4 cols)
    const int rw  = tid >> 6;            // row within pass
    const int jc  = cg << 2;
    const int bt  = blockIdx.y;          // 0..31
    const int t   = bt & 7;
    const int i0  = blockIdx.x << 4;

    // zero halo columns (j=-1 -> idx 3, j=256 -> idx 260)
    if (tid < 18){ ys[tid*YSW + 3] = 0.0f; ys[tid*YSW + 260] = 0.0f; }

    // ---- phase 1: y = A(x) on rows i0-1 .. i0+16 ----
    for (int p = 0; p < 5; ++p){
        int yr = p*4 + rw;               // wave-uniform branch
        if (yr < 18){
            int iy = i0 - 1 + yr;
            float y[4] = {0,0,0,0};
            if (iy >= 0 && iy < 256){
                int pix = (bt << 16) + (iy << 8) + jc;
                int rb  = pix - jc;
                float vc[6], vn[6], vs[6];
                row6(x, rb, jc, vc);
                if (iy < 255) row6(x, rb + 256, jc, vn);
                else { vn[0]=vn[1]=vn[2]=vn[3]=vn[4]=vn[5]=0.0f; }
                if (iy > 0) row6(x, rb - 256, jc, vs);
                else { vs[0]=vs[1]=vs[2]=vs[3]=vs[4]=vs[5]=0.0f; }
                float k2[4], m1[4], m2[4], hx[4], hs[4], hy[4];
                ldf4(&fld[0*F_ELEMS + pix], k2);
                ldf4(&fld[1*F_ELEMS + pix], m1);
                ldf4(&fld[2*F_ELEMS + pix], m2);
                ldf4(&fld[3*F_ELEMS + pix], hx);
                ldf4(&fld[4*F_ELEMS + pix], hs);
                ldf4(&fld[5*F_ELEMS + pix], hy);
                stencil4(k2, m1, m2, hx, hs, hy, vc, vn, vs, y);
            }
            float4 y4 = make_float4(y[0], y[1], y[2], y[3]);
            *(float4*)&ys[yr*YSW + 4 + jc] = y4;
        }
    }
    __syncthreads();

    // ---- phase 2: z = A(y); accumulate D*r^2 and prod(tau) ----
    float local = 0.0f;
    float lprod = 1.0f;                  // product of 16 taus, range safe in f32
    #pragma unroll
    for (int p = 0; p < 4; ++p){
        int zr = p*4 + rw;               // 0..15
        int iz = i0 + zr;
        int pix = (bt << 16) + (iz << 8) + jc;
        int base = (zr + 1)*YSW + 4 + jc;

        float vc[6], vn[6], vs[6];
        {
            float4 c4 = *(const float4*)&ys[base];
            vc[1]=c4.x; vc[2]=c4.y; vc[3]=c4.z; vc[4]=c4.w;
            vc[0]=ys[base-1]; vc[5]=ys[base+4];
            float4 n4 = *(const float4*)&ys[base+YSW];
            vn[1]=n4.x; vn[2]=n4.y; vn[3]=n4.z; vn[4]=n4.w;
            vn[0]=ys[base+YSW-1]; vn[5]=ys[base+YSW+4];
            float4 s4 = *(const float4*)&ys[base-YSW];
            vs[1]=s4.x; vs[2]=s4.y; vs[3]=s4.z; vs[4]=s4.w;
            vs[0]=ys[base-YSW-1]; vs[5]=ys[base-YSW+4];
        }
        float k2[4], m1[4], m2[4], hx[4], hs[4], hy[4], tv[4], z[4];
        ldf4(&fld[0*F_ELEMS + pix], k2);
        ldf4(&fld[1*F_ELEMS + pix], m1);
        ldf4(&fld[2*F_ELEMS + pix], m2);
        ldf4(&fld[3*F_ELEMS + pix], hx);
        ldf4(&fld[4*F_ELEMS + pix], hs);
        ldf4(&fld[5*F_ELEMS + pix], hy);
        ldf4(&fld[6*F_ELEMS + pix], tv);     // tau
        stencil4(k2, m1, m2, hx, hs, hy, vc, vn, vs, z);

        float4 xc = *(const float4*)&x[pix];
        float4 xp = make_float4(0,0,0,0);
        if (t > 0) xp = *(const float4*)&x[pix - IMG];
        const float* xcp = (const float*)&xc;
        const float* xpp = (const float*)&xp;
        #pragma unroll
        for (int q = 0; q < 4; ++q){
            float r = xcp[q] + z[q] - xpp[q];
            float dq = 1.0f/(tv[q]*tv[q]);   // D = 1/tau^2 in f32
            local += dq*r*r;
        }
        lprod *= tv[0]*tv[1];
        lprod *= tv[2]*tv[3];
    }

    // ---- reduction: wave shfl butterfly, then 4 partials ----
    float a = local;
    float b = __logf(lprod);             // sum(log tau) via single log of product
    #pragma unroll
    for (int off = 32; off > 0; off >>= 1){
        a += __shfl_down(a, off);
        b += __shfl_down(b, off);
    }
    if (cg == 0){ redA[rw] = a; redB[rw] = b; }
    __syncthreads();
    if (tid == 0){
        float ra = redA[0] + redA[1] + redA[2] + redA[3];
        float rb = redB[0] + redB[1] + redB[2] + redB[3];
        atomicAdd(out, 0.5f*ra + rb);    // 0.5*xQx - 0.5*logdetD
    }
}

extern "C" void kernel_launch(void* const* d_in, const int* in_sizes, int n_in,
                              void* d_out, int out_size, void* d_ws, size_t ws_size,
                              hipStream_t stream)
{
    const float* x = (const float*)d_in[0];
    const float* w = (const float*)d_in[1];
    float* out = (float*)d_out;
    _Float16* fld = (_Float16*)d_ws;

    conv_mfma<<<dim3(128, 4), 256, 0, stream>>>(x, w, fld, out);
    fused_A<<<dim3(16, 32), 256, 0, stream>>>(x, fld, out);
}

// Round 2
// 99.382 us; speedup vs baseline: 1.0849x; 1.0096x over previous
//
#include <hip/hip_runtime.h>

#define F_ELEMS 2097152            // B*T*H*W = 4*8*256*256 (elements per field)
#define IMG 65536                  // H*W

typedef _Float16 half8  __attribute__((ext_vector_type(8)));
typedef _Float16 half2v __attribute__((ext_vector_type(2)));
typedef _Float16 half4v __attribute__((ext_vector_type(4)));
typedef float    floatx4 __attribute__((ext_vector_type(4)));

__device__ __forceinline__ float sigm(float x){ return 1.0f/(1.0f + __expf(-x)); }
__device__ __forceinline__ float tanh_fast(float x){
    float t = __expf(2.0f*x);
    return 1.0f - 2.0f/(t + 1.0f);
}

// ---------------------------------------------------------------------------
// K1: conv 3x3 (8ch -> 64ch) via MFMA f16 implicit GEMM, fused pointwise.
// Block: strip of 2 rows x 256 cols for one b; computes all 64 oc.
// K decomposition: MFMA 16x16x32: K=32 = 4 taps x 8 input channels.
// OPERAND-SWAPPED MFMA: A = pixel patches, B = weights. D[m=px][n=oc], so
// each lane holds 4 CONSECUTIVE PIXELS of one oc -> half4 (8B) stores, 4
// store instructions per iter instead of 14-16 scalar f16 stores.
// Fields stored f16: 0 kappa^2, 1 m1, 2 m2, 3 Hxx, 4 Hs, 5 Hyy, 6 tau.
// ---------------------------------------------------------------------------
__global__ __launch_bounds__(256) void conv_mfma(
    const float* __restrict__ x, const float* __restrict__ w,
    _Float16* __restrict__ fld, float* __restrict__ out)
{
    __shared__ _Float16 xt[4*258*8];     // 4 rows, 258 cols (halo), 8 ch
    __shared__ _Float16 Wl[12*64*8];     // [tap][oc][c]

    const int tid = threadIdx.x;
    const int i0  = blockIdx.x << 1;     // strip of 2 rows
    const int b   = blockIdx.y;

    // K2 runs after K1 in stream order, so this zero is safe (no atomics here).
    if (tid == 0 && blockIdx.x == 0 && blockIdx.y == 0) out[0] = 0.0f;

    // ---- stage x (f32 -> f16, channel pairs for 4B LDS writes) ----
    for (int e = tid; e < 258*4*4; e += 256){
        int cc = e % 258;
        int rr = (e/258) & 3;
        int cp = e / (258*4);            // channel pair 0..3
        int gi = i0 - 1 + rr, gj = cc - 1;
        float v0 = 0.0f, v1 = 0.0f;
        if (gi >= 0 && gi < 256 && gj >= 0 && gj < 256){
            int base = ((b*8 + 2*cp) << 16) + (gi << 8) + gj;
            v0 = x[base];
            v1 = x[base + IMG];
        }
        half2v h; h[0] = (_Float16)v0; h[1] = (_Float16)v1;
        *(half2v*)&xt[(rr*258 + cc)*8 + 2*cp] = h;
    }
    // ---- stage weights [tap][oc][c], zero-pad taps 9..11 ----
    for (int e = tid; e < 12*64*8; e += 256){
        int c  = e & 7;
        int oc = (e >> 3) & 63;
        int t  = e >> 9;
        float v = (t < 9) ? w[(oc*8 + c)*9 + t] : 0.0f;
        Wl[e] = (_Float16)v;             // e == (t*64+oc)*8 + c
    }
    __syncthreads();

    const int lane = tid & 63;
    const int quad = lane >> 4;
    const int l16  = lane & 15;
    const int wv   = tid >> 6;

    // Weight frags (now the B operand): B[k=quad*8+j][n=oc=ot*16+l16]
    //   -> Wl[tap=s*4+quad][ot*16+l16][0..7]
    half8 afr[4][3];
    int boff[3];
    #pragma unroll
    for (int s = 0; s < 3; ++s){
        int t  = s*4 + quad;
        afr[0][s] = *(const half8*)&Wl[(t*64 +  0 + l16)*8];
        afr[1][s] = *(const half8*)&Wl[(t*64 + 16 + l16)*8];
        afr[2][s] = *(const half8*)&Wl[(t*64 + 32 + l16)*8];
        afr[3][s] = *(const half8*)&Wl[(t*64 + 48 + l16)*8];
        int tc = (t < 9) ? t : 8;        // taps >=9 have zero weights
        int dh = tc / 3, dw = tc - dh*3;
        boff[s] = (dh*258 + dw)*8;
    }

    // it-invariant epilogue constants: lane (quad,l16) holds px = base+quad*4+rg
    // of oc = ot*16 + l16.
    const bool lo  = (l16 < 8);
    const int  tlo = l16 << 16, thi = (l16 - 8) << 16;
    const int  off0 = lo ? (0*F_ELEMS + tlo) : (1*F_ELEMS + thi);  // kappa^2 / m1
    const int  off1 = lo ? (2*F_ELEMS + tlo) : (3*F_ELEMS + thi);  // m2 / Hxx
    const int  off2 = 4*F_ELEMS + tlo;                             // Hs (lo only)
    const int  off3 = lo ? (5*F_ELEMS + tlo) : (6*F_ELEMS + thi);  // Hyy / tau

    // 32 groups of 16 px (2 rows x 16 col-groups); 8 iters per wave
    #pragma unroll 2
    for (int it = 0; it < 8; ++it){
        const int g   = it*4 + wv;
        const int r   = g >> 4;
        const int jb  = ((g & 15) << 4) + l16;   // A-frag row = px = l16
        const int xoff = (r*258 + jb)*8;

        floatx4 acc0 = {0,0,0,0}, acc1 = {0,0,0,0}, acc2 = {0,0,0,0}, acc3 = {0,0,0,0};
        #pragma unroll
        for (int s = 0; s < 3; ++s){
            half8 bf = *(const half8*)&xt[xoff + boff[s]];
            acc0 = __builtin_amdgcn_mfma_f32_16x16x32_f16(bf, afr[0][s], acc0, 0, 0, 0);
            acc1 = __builtin_amdgcn_mfma_f32_16x16x32_f16(bf, afr[1][s], acc1, 0, 0, 0);
            acc2 = __builtin_amdgcn_mfma_f32_16x16x32_f16(bf, afr[2][s], acc2, 0, 0, 0);
            acc3 = __builtin_amdgcn_mfma_f32_16x16x32_f16(bf, afr[3][s], acc3, 0, 0, 0);
        }

        // epilogue: lane holds px = jb0 + quad*4 + rg (rg=0..3) of oc = ot*16+l16
        const int jb0  = (g & 15) << 4;
        const int pixb = (b << 19) + ((i0 + r) << 8) + jb0 + (quad << 2);

        half4v h0, h1, h2, h3;
        #pragma unroll
        for (int rg = 0; rg < 4; ++rg){
            // ot=0: oc=l16: kappa (l16<8) / m1 (l16>=8)
            float v0 = acc0[rg];
            float s0 = 0.99f*sigm(v0) + 0.01f;
            h0[rg] = (_Float16)(lo ? s0*s0 : v0);
            // ot=1: m2 (l16<8) / Hxx (l16>=8)
            float v1 = acc1[rg];
            h1[rg] = (_Float16)(lo ? v1 : 0.99f*sigm(v1) + 0.01f);
            // ot=2: Hxy (l16<8) + Hyx (l16>=8) -> Hs on lo lanes
            float th  = 0.1f*tanh_fast(acc2[rg]);
            float oth = __shfl_xor(th, 8, 64);
            h2[rg] = (_Float16)(th + oth);
            // ot=3: Hyy (l16<8) / tau (l16>=8)
            float sg = sigm(acc3[rg]);
            h3[rg] = (_Float16)(lo ? 0.99f*sg + 0.01f : 9.9f*sg + 0.1f);
        }
        *(half4v*)&fld[off0 + pixb] = h0;
        *(half4v*)&fld[off1 + pixb] = h1;
        if (lo) *(half4v*)&fld[off2 + pixb] = h2;
        *(half4v*)&fld[off3 + pixb] = h3;
    }
}

// ---------------------------------------------------------------------------
// A(u) with f16 coefficient fields.
// ---------------------------------------------------------------------------
__device__ __forceinline__ void ldf4(const _Float16* __restrict__ p, float o[4]){
    half4v h = *(const half4v*)p;
    o[0] = (float)h[0]; o[1] = (float)h[1]; o[2] = (float)h[2]; o[3] = (float)h[3];
}

__device__ __forceinline__ void row6(const float* __restrict__ u, int rb, int j0, float v[6]){
    const float4 c4 = *(const float4*)&u[rb + j0];
    v[1] = c4.x; v[2] = c4.y; v[3] = c4.z; v[4] = c4.w;
    v[0] = (j0 > 0)   ? u[rb + j0 - 1] : 0.0f;
    v[5] = (j0 < 252) ? u[rb + j0 + 4] : 0.0f;
}

__device__ __forceinline__ void stencil4(const float k2[4], const float m1[4],
    const float m2[4], const float hx[4], const float hs[4], const float hy[4],
    const float vc[6], const float vn[6], const float vs[6], float rp[4])
{
    #pragma unroll
    for (int p = 0; p < 4; ++p){
        float hxx = hx[p], hyy = hy[p];
        rp[p] = (k2[p] + 2.0f*(hxx + hyy))*vc[p+1]
              + (0.5f*m1[p] - hxx)*vc[p+2]
              - (0.5f*m1[p] + hxx)*vc[p]
              + (0.5f*m2[p] - hyy)*vn[p+1]
              - (0.5f*m2[p] + hyy)*vs[p+1]
              - 0.25f*hs[p]*(vn[p+2] - vs[p+2] - vn[p] + vs[p]);
    }
}

// ---------------------------------------------------------------------------
// K2: fused z = A(A(x)); r = x + z - x_prev;
// out += 0.5*sum(D r^2) + sum(log tau)   (== 0.5*(xQx - logdetD))
// Block: 16-row strip x 256 cols of one (b,t) image. y kept in LDS (18 rows
// incl. halo, recomputed per strip).
// ---------------------------------------------------------------------------
#define YSW 268
__global__ __launch_bounds__(256) void fused_A(
    const float* __restrict__ x, const _Float16* __restrict__ fld,
    float* __restrict__ out)
{
    __shared__ float ys[18*YSW];
    __shared__ float redA[4], redB[4];

    const int tid = threadIdx.x;
    const int cg  = tid & 63;            // col group (4 cols)
    const int rw  = tid >> 6;            // row within pass
    const int jc  = cg << 2;
    const int bt  = blockIdx.y;          // 0..31
    const int t   = bt & 7;
    const int i0  = blockIdx.x << 4;

    // zero halo columns (j=-1 -> idx 3, j=256 -> idx 260)
    if (tid < 18){ ys[tid*YSW + 3] = 0.0f; ys[tid*YSW + 260] = 0.0f; }

    // ---- phase 1: y = A(x) on rows i0-1 .. i0+16 ----
    for (int p = 0; p < 5; ++p){
        int yr = p*4 + rw;               // wave-uniform branch
        if (yr < 18){
            int iy = i0 - 1 + yr;
            float y[4] = {0,0,0,0};
            if (iy >= 0 && iy < 256){
                int pix = (bt << 16) + (iy << 8) + jc;
                int rb  = pix - jc;
                float vc[6], vn[6], vs[6];
                row6(x, rb, jc, vc);
                if (iy < 255) row6(x, rb + 256, jc, vn);
                else { vn[0]=vn[1]=vn[2]=vn[3]=vn[4]=vn[5]=0.0f; }
                if (iy > 0) row6(x, rb - 256, jc, vs);
                else { vs[0]=vs[1]=vs[2]=vs[3]=vs[4]=vs[5]=0.0f; }
                float k2[4], m1[4], m2[4], hx[4], hs[4], hy[4];
                ldf4(&fld[0*F_ELEMS + pix], k2);
                ldf4(&fld[1*F_ELEMS + pix], m1);
                ldf4(&fld[2*F_ELEMS + pix], m2);
                ldf4(&fld[3*F_ELEMS + pix], hx);
                ldf4(&fld[4*F_ELEMS + pix], hs);
                ldf4(&fld[5*F_ELEMS + pix], hy);
                stencil4(k2, m1, m2, hx, hs, hy, vc, vn, vs, y);
            }
            float4 y4 = make_float4(y[0], y[1], y[2], y[3]);
            *(float4*)&ys[yr*YSW + 4 + jc] = y4;
        }
    }
    __syncthreads();

    // ---- phase 2: z = A(y); accumulate D*r^2 and prod(tau) ----
    float local = 0.0f;
    float lprod = 1.0f;                  // product of 16 taus, range safe in f32
    #pragma unroll
    for (int p = 0; p < 4; ++p){
        int zr = p*4 + rw;               // 0..15
        int iz = i0 + zr;
        int pix = (bt << 16) + (iz << 8) + jc;
        int base = (zr + 1)*YSW + 4 + jc;

        float vc[6], vn[6], vs[6];
        {
            float4 c4 = *(const float4*)&ys[base];
            vc[1]=c4.x; vc[2]=c4.y; vc[3]=c4.z; vc[4]=c4.w;
            vc[0]=ys[base-1]; vc[5]=ys[base+4];
            float4 n4 = *(const float4*)&ys[base+YSW];
            vn[1]=n4.x; vn[2]=n4.y; vn[3]=n4.z; vn[4]=n4.w;
            vn[0]=ys[base+YSW-1]; vn[5]=ys[base+YSW+4];
            float4 s4 = *(const float4*)&ys[base-YSW];
            vs[1]=s4.x; vs[2]=s4.y; vs[3]=s4.z; vs[4]=s4.w;
            vs[0]=ys[base-YSW-1]; vs[5]=ys[base-YSW+4];
        }
        float k2[4], m1[4], m2[4], hx[4], hs[4], hy[4], tv[4], z[4];
        ldf4(&fld[0*F_ELEMS + pix], k2);
        ldf4(&fld[1*F_ELEMS + pix], m1);
        ldf4(&fld[2*F_ELEMS + pix], m2);
        ldf4(&fld[3*F_ELEMS + pix], hx);
        ldf4(&fld[4*F_ELEMS + pix], hs);
        ldf4(&fld[5*F_ELEMS + pix], hy);
        ldf4(&fld[6*F_ELEMS + pix], tv);     // tau
        stencil4(k2, m1, m2, hx, hs, hy, vc, vn, vs, z);

        float4 xc = *(const float4*)&x[pix];
        float4 xp = make_float4(0,0,0,0);
        if (t > 0) xp = *(const float4*)&x[pix - IMG];
        const float* xcp = (const float*)&xc;
        const float* xpp = (const float*)&xp;
        #pragma unroll
        for (int q = 0; q < 4; ++q){
            float r = xcp[q] + z[q] - xpp[q];
            float dq = 1.0f/(tv[q]*tv[q]);   // D = 1/tau^2 in f32
            local += dq*r*r;
        }
        lprod *= tv[0]*tv[1];
        lprod *= tv[2]*tv[3];
    }

    // ---- reduction: wave shfl butterfly, then 4 partials ----
    float a = local;
    float b = __logf(lprod);             // sum(log tau) via single log of product
    #pragma unroll
    for (int off = 32; off > 0; off >>= 1){
        a += __shfl_down(a, off);
        b += __shfl_down(b, off);
    }
    if (cg == 0){ redA[rw] = a; redB[rw] = b; }
    __syncthreads();
    if (tid == 0){
        float ra = redA[0] + redA[1] + redA[2] + redA[3];
        float rb = redB[0] + redB[1] + redB[2] + redB[3];
        atomicAdd(out, 0.5f*ra + rb);    // 0.5*xQx - 0.5*logdetD
    }
}

extern "C" void kernel_launch(void* const* d_in, const int* in_sizes, int n_in,
                              void* d_out, int out_size, void* d_ws, size_t ws_size,
                              hipStream_t stream)
{
    const float* x = (const float*)d_in[0];
    const float* w = (const float*)d_in[1];
    float* out = (float*)d_out;
    _Float16* fld = (_Float16*)d_ws;

    conv_mfma<<<dim3(128, 4), 256, 0, stream>>>(x, w, fld, out);
    fused_A<<<dim3(16, 32), 256, 0, stream>>>(x, fld, out);
}